// Round 3
// baseline (44.399 us; speedup 1.0000x reference)
//
#include <hip/hip_runtime.h>

// Problem constants (from reference setup_inputs)
constexpr int B    = 8;
constexpr int N    = 4096;
constexpr int CIN  = 6;
constexpr int NC   = 3;
constexpr int NP   = 1024;
constexpr int C0   = CIN + NC;   // 9
constexpr int M1   = 64;
constexpr int M2   = 64;
constexpr int M3   = 128;
constexpr int NPTS = B * NP;     // 8192 points total
constexpr float EPS = 1e-5f;

// d_out layout: [grouped_xyz zeros: B*NP*64*3] ++ [pooled: B*M3*NP]
constexpr int GZ_ELEMS = B * NP * 64 * 3;      // 1,572,864
// d_ws layout (floats):
constexpr size_t Y1_OFF = 0;
constexpr size_t Y2_OFF = Y1_OFF + (size_t)M1 * NPTS;
constexpr size_t Y3_OFF = Y2_OFF + (size_t)M2 * NPTS;
constexpr size_t AB1_OFF = Y3_OFF + (size_t)M3 * NPTS;
constexpr size_t AB2_OFF = AB1_OFF + 2 * M1;
constexpr size_t AB3_OFF = AB2_OFF + 2 * M2;

// ---------------- Zero-fill for grouped_xyz (replaces slow rocclr fill) ------
// GZ_ELEMS * 4 B = 6 MB = 393216 float4s; 1536 blocks x 256 thr x 1 float4.
__global__ void k_zero(float4* __restrict__ out) {
    int gid = blockIdx.x * blockDim.x + threadIdx.x;
    out[gid] = make_float4(0.f, 0.f, 0.f, 0.f);
}

// ---------------- Kernel 1: gather features + layer-1 GEMM ----------------
// Grid: (M1/OC1) * (NPTS/256) blocks; each thread: 1 point, OC1 outputs.
constexpr int OC1 = 8;
__global__ void k_gather_l1(const float* __restrict__ points,
                            const float* __restrict__ onehot,
                            const int* __restrict__ idx,
                            const float* __restrict__ w1,
                            float* __restrict__ y1) {
    constexpr int NOB = M1 / OC1;             // 8 output-chunks
    __shared__ float ws[OC1 * C0];
    int t = threadIdx.x;
    int ob = blockIdx.x % NOB;                // which output chunk
    int pb = blockIdx.x / NOB;                // which point block
    int o0 = ob * OC1;
    if (t < OC1 * C0) ws[t] = w1[o0 * C0 + t];
    __syncthreads();

    int p  = pb * blockDim.x + t;             // 0..NPTS-1
    int b  = p >> 10;                         // /NP
    int pp = p & (NP - 1);
    int n  = idx[b * NP + pp];

    float f[C0];
#pragma unroll
    for (int c = 0; c < CIN; ++c) f[c] = points[((size_t)b * CIN + c) * N + n];
#pragma unroll
    for (int c = 0; c < NC; ++c)  f[CIN + c] = onehot[b * NC + c];

#pragma unroll
    for (int o = 0; o < OC1; ++o) {
        float acc = 0.f;
#pragma unroll
        for (int c = 0; c < C0; ++c) acc += ws[o * C0 + c] * f[c];
        y1[(size_t)(o0 + o) * NPTS + p] = acc;
    }
}

// ---------------- Stats: one block per channel, deterministic reduce ----------------
__device__ inline void block_reduce2(float& s, float& s2) {
    for (int off = 32; off; off >>= 1) {
        s  += __shfl_down(s,  off, 64);
        s2 += __shfl_down(s2, off, 64);
    }
    __shared__ float ls[4], ls2[4];
    int lane = threadIdx.x & 63;
    int w    = threadIdx.x >> 6;
    if (lane == 0) { ls[w] = s; ls2[w] = s2; }
    __syncthreads();
    if (threadIdx.x == 0) {
        for (int i = 1; i < 4; ++i) { s += ls[i]; s2 += ls2[i]; }
    }
}

__global__ void k_stats(const float* __restrict__ y,
                        const float* __restrict__ gamma,
                        const float* __restrict__ beta,
                        float* __restrict__ AB) {
    int c = blockIdx.x;
    const float4* yc4 = (const float4*)(y + (size_t)c * NPTS);
    float s = 0.f, s2 = 0.f;
#pragma unroll
    for (int i = threadIdx.x; i < NPTS / 4; i += 256) {
        float4 v = yc4[i];
        s  += v.x + v.y + v.z + v.w;
        s2 += v.x * v.x + v.y * v.y + v.z * v.z + v.w * v.w;
    }
    block_reduce2(s, s2);
    if (threadIdx.x == 0) {
        float inv_n = 1.0f / (float)NPTS;
        float mean = s * inv_n;
        float var  = s2 * inv_n - mean * mean;
        float istd = rsqrtf(var + EPS);
        float A = gamma[c] * istd;
        float Bb = beta[c] - mean * A;
        AB[2 * c]     = A;
        AB[2 * c + 1] = Bb;
    }
}

// ---------------- Middle layers: normalize+relu previous, GEMM ----------------
// Grid: (CO/OC) * (NPTS/256); each thread: 1 point, OC outputs.
template <int CI, int CO, int OC>
__global__ void k_mlp(const float* __restrict__ yin,
                      const float* __restrict__ AB,
                      const float* __restrict__ w,
                      float* __restrict__ yout) {
    constexpr int NOB = CO / OC;
    __shared__ float ws[OC * CI];
    __shared__ float sAB[2 * CI];
    int t = threadIdx.x;
    int ob = blockIdx.x % NOB;
    int pb = blockIdx.x / NOB;
    int o0 = ob * OC;
    for (int i = t; i < OC * CI; i += blockDim.x) ws[i] = w[o0 * CI + i];
    if (t < 2 * CI) sAB[t] = AB[t];
    __syncthreads();

    int p = pb * blockDim.x + t;

    float x[CI];
#pragma unroll
    for (int c = 0; c < CI; ++c) {
        float v = yin[(size_t)c * NPTS + p] * sAB[2 * c] + sAB[2 * c + 1];
        x[c] = v > 0.f ? v : 0.f;
    }
#pragma unroll
    for (int o = 0; o < OC; ++o) {
        float acc = 0.f;
#pragma unroll
        for (int c = 0; c < CI; ++c) acc += ws[o * CI + c] * x[c];
        yout[(size_t)(o0 + o) * NPTS + p] = acc;
    }
}

// ---------------- Final: normalize+relu layer 3, write pooled (float4) ----------------
__global__ void k_out(const float* __restrict__ y3,
                      const float* __restrict__ AB,
                      float* __restrict__ out) {
    int gid = blockIdx.x * blockDim.x + threadIdx.x;   // over B*M3*NP/4
    int e0  = gid * 4;                                 // element index
    int pp  = e0 & (NP - 1);
    int c   = (e0 >> 10) & (M3 - 1);
    int b   = e0 >> 17;
    float A  = AB[2 * c];
    float Bb = AB[2 * c + 1];
    const float4 v = *(const float4*)(y3 + (size_t)c * NPTS + b * NP + pp);
    float4 r;
    r.x = fmaxf(v.x * A + Bb, 0.f);
    r.y = fmaxf(v.y * A + Bb, 0.f);
    r.z = fmaxf(v.z * A + Bb, 0.f);
    r.w = fmaxf(v.w * A + Bb, 0.f);
    *(float4*)(out + e0) = r;
}

extern "C" void kernel_launch(void* const* d_in, const int* in_sizes, int n_in,
                              void* d_out, int out_size, void* d_ws, size_t ws_size,
                              hipStream_t stream) {
    const float* points = (const float*)d_in[1];
    const float* onehot = (const float*)d_in[2];
    const int*   idx    = (const int*)d_in[3];
    const float* w1 = (const float*)d_in[4];
    const float* g1 = (const float*)d_in[5];
    const float* b1 = (const float*)d_in[6];
    const float* w2 = (const float*)d_in[7];
    const float* g2 = (const float*)d_in[8];
    const float* b2 = (const float*)d_in[9];
    const float* w3 = (const float*)d_in[10];
    const float* g3 = (const float*)d_in[11];
    const float* b3 = (const float*)d_in[12];

    float* out = (float*)d_out;
    float* ws  = (float*)d_ws;
    float* y1  = ws + Y1_OFF;
    float* y2  = ws + Y2_OFF;
    float* y3  = ws + Y3_OFF;
    float* AB1 = ws + AB1_OFF;
    float* AB2 = ws + AB2_OFF;
    float* AB3 = ws + AB3_OFF;

    const int T = 256;
    const int PBLK = NPTS / T;   // 32

    // Output 0: grouped_xyz is exactly zeros (cxt - cxt broadcast).
    // Custom fill: runtime's fillBufferAligned took ~40us; this takes ~2us.
    k_zero<<<GZ_ELEMS / 4 / T, T, 0, stream>>>((float4*)d_out);

    k_gather_l1<<<(M1 / OC1) * PBLK, T, 0, stream>>>(points, onehot, idx, w1, y1);
    k_stats<<<M1, T, 0, stream>>>(y1, g1, b1, AB1);
    k_mlp<M1, M2, 8><<<(M2 / 8) * PBLK, T, 0, stream>>>(y1, AB1, w2, y2);
    k_stats<<<M2, T, 0, stream>>>(y2, g2, b2, AB2);
    k_mlp<M2, M3, 8><<<(M3 / 8) * PBLK, T, 0, stream>>>(y2, AB2, w3, y3);
    k_stats<<<M3, T, 0, stream>>>(y3, g3, b3, AB3);
    k_out<<<(B * M3 * NP / 4) / T, T, 0, stream>>>(y3, AB3, out + GZ_ELEMS);
}

// Round 4
// 37.023 us; speedup vs baseline: 1.1992x; 1.1992x over previous
//
#include <hip/hip_runtime.h>

// Problem constants (from reference setup_inputs)
constexpr int B    = 8;
constexpr int N    = 4096;
constexpr int CIN  = 6;
constexpr int NC   = 3;
constexpr int NP   = 1024;
constexpr int C0   = CIN + NC;   // 9
constexpr int M1   = 64;
constexpr int M2   = 64;
constexpr int M3   = 128;
constexpr int NPTS = B * NP;     // 8192 points total
constexpr int NPB  = NPTS / 256; // 32 point-blocks
constexpr float EPS = 1e-5f;

// d_out layout: [grouped_xyz zeros: B*NP*64*3] ++ [pooled: B*M3*NP]
constexpr int GZ_ELEMS = B * NP * 64 * 3;      // 1,572,864 floats = 6 MB
constexpr int GZ_F4    = GZ_ELEMS / 4;         // 393,216 float4
// d_ws layout (floats):
constexpr size_t Y1_OFF = 0;
constexpr size_t Y2_OFF = Y1_OFF + (size_t)M1 * NPTS;
constexpr size_t Y3_OFF = Y2_OFF + (size_t)M2 * NPTS;
constexpr size_t PS1_OFF = Y3_OFF + (size_t)M3 * NPTS;   // [M1][NPB] sums
constexpr size_t PQ1_OFF = PS1_OFF + (size_t)M1 * NPB;   // [M1][NPB] sumsq
constexpr size_t PS2_OFF = PQ1_OFF + (size_t)M1 * NPB;
constexpr size_t PQ2_OFF = PS2_OFF + (size_t)M2 * NPB;
constexpr size_t PS3_OFF = PQ2_OFF + (size_t)M2 * NPB;
constexpr size_t PQ3_OFF = PS3_OFF + (size_t)M3 * NPB;

// Deterministic per-block partial sums for OC channels -> ps/pq [ch][NPB].
template <int OC>
__device__ inline void emit_partials(const float (&acc)[OC], int o0, int pb,
                                     float* __restrict__ ps, float* __restrict__ pq) {
    float sv[OC], qv[OC];
#pragma unroll
    for (int o = 0; o < OC; ++o) { sv[o] = acc[o]; qv[o] = acc[o] * acc[o]; }
#pragma unroll
    for (int off = 32; off; off >>= 1) {
#pragma unroll
        for (int o = 0; o < OC; ++o) {
            sv[o] += __shfl_down(sv[o], off, 64);
            qv[o] += __shfl_down(qv[o], off, 64);
        }
    }
    __shared__ float rs[OC][4], rq[OC][4];
    int lane = threadIdx.x & 63, w = threadIdx.x >> 6;
    if (lane == 0) {
#pragma unroll
        for (int o = 0; o < OC; ++o) { rs[o][w] = sv[o]; rq[o][w] = qv[o]; }
    }
    __syncthreads();
    if (threadIdx.x < OC) {
        int o = threadIdx.x;
        float s = rs[o][0] + rs[o][1] + rs[o][2] + rs[o][3];
        float q = rq[o][0] + rq[o][1] + rq[o][2] + rq[o][3];
        ps[(o0 + o) * NPB + pb] = s;
        pq[(o0 + o) * NPB + pb] = q;
    }
}

// Consumer prologue: fold [CI][NPB] partials into per-channel A,B in LDS.
template <int CI>
__device__ inline void fold_AB(const float* __restrict__ ps, const float* __restrict__ pq,
                               const float* __restrict__ gamma, const float* __restrict__ beta,
                               float* __restrict__ sAB) {
    int t = threadIdx.x;
    if (t < CI) {
        float s = 0.f, q = 0.f;
#pragma unroll 8
        for (int i = 0; i < NPB; ++i) { s += ps[t * NPB + i]; q += pq[t * NPB + i]; }
        float inv_n = 1.0f / (float)NPTS;
        float mean = s * inv_n;
        float var  = q * inv_n - mean * mean;
        float A = gamma[t] * rsqrtf(var + EPS);
        sAB[2 * t]     = A;
        sAB[2 * t + 1] = beta[t] - mean * A;
    }
}

// ---------------- k1: zero grouped_xyz + gather + layer-1 GEMM + partials ----
constexpr int OC1 = 8;
__global__ void k1_gather(const float* __restrict__ points,
                          const float* __restrict__ onehot,
                          const int* __restrict__ idx,
                          const float* __restrict__ w1,
                          float* __restrict__ y1,
                          float* __restrict__ ps1, float* __restrict__ pq1,
                          float4* __restrict__ gz) {
    constexpr int NOB = M1 / OC1;             // 8
    __shared__ float ws[OC1 * C0];
    int t = threadIdx.x;
    int ob = blockIdx.x % NOB;
    int pb = blockIdx.x / NOB;
    int o0 = ob * OC1;
    if (t < OC1 * C0) ws[t] = w1[o0 * C0 + t];

    // zero-fill slice of grouped_xyz: 256 blocks x 1536 float4
    {
        constexpr int PER_BLK = GZ_F4 / (NOB * NPB);   // 1536
        float4 z = make_float4(0.f, 0.f, 0.f, 0.f);
        float4* g = gz + (size_t)blockIdx.x * PER_BLK + t;
#pragma unroll
        for (int i = 0; i < PER_BLK / 256; ++i) g[i * 256] = z;
    }
    __syncthreads();

    int p  = pb * 256 + t;
    int b  = p >> 10;
    int pp = p & (NP - 1);
    int n  = idx[b * NP + pp];

    float f[C0];
#pragma unroll
    for (int c = 0; c < CIN; ++c) f[c] = points[((size_t)b * CIN + c) * N + n];
#pragma unroll
    for (int c = 0; c < NC; ++c)  f[CIN + c] = onehot[b * NC + c];

    float acc[OC1];
#pragma unroll
    for (int o = 0; o < OC1; ++o) {
        float a = 0.f;
#pragma unroll
        for (int c = 0; c < C0; ++c) a += ws[o * C0 + c] * f[c];
        acc[o] = a;
        y1[(size_t)(o0 + o) * NPTS + p] = a;
    }
    emit_partials<OC1>(acc, o0, pb, ps1, pq1);
}

// ---------------- k2/k3: BN(prev)+ReLU + GEMM + partials ----------------
template <int CI, int CO, int OC>
__global__ void k_mlp(const float* __restrict__ yin,
                      const float* __restrict__ psin, const float* __restrict__ pqin,
                      const float* __restrict__ gamma, const float* __restrict__ beta,
                      const float* __restrict__ w,
                      float* __restrict__ yout,
                      float* __restrict__ psout, float* __restrict__ pqout) {
    constexpr int NOB = CO / OC;
    __shared__ float ws[OC * CI];
    __shared__ float sAB[2 * CI];
    int t = threadIdx.x;
    int ob = blockIdx.x % NOB;
    int pb = blockIdx.x / NOB;
    int o0 = ob * OC;

    fold_AB<CI>(psin, pqin, gamma, beta, sAB);
    for (int i = t; i < OC * CI; i += 256) ws[i] = w[o0 * CI + i];
    __syncthreads();

    int p = pb * 256 + t;
    float x[CI];
#pragma unroll
    for (int c = 0; c < CI; ++c) {
        float v = yin[(size_t)c * NPTS + p] * sAB[2 * c] + sAB[2 * c + 1];
        x[c] = v > 0.f ? v : 0.f;
    }
    float acc[OC];
#pragma unroll
    for (int o = 0; o < OC; ++o) {
        float a = 0.f;
#pragma unroll
        for (int c = 0; c < CI; ++c) a += ws[o * CI + c] * x[c];
        acc[o] = a;
        yout[(size_t)(o0 + o) * NPTS + p] = a;
    }
    __syncthreads();   // reuse of shared arrays in emit_partials
    emit_partials<OC>(acc, o0, pb, psout, pqout);
}

// ---------------- k4: BN3+ReLU, write pooled. One block per (b,c) row. ------
__global__ void k_out(const float* __restrict__ y3,
                      const float* __restrict__ ps, const float* __restrict__ pq,
                      const float* __restrict__ gamma, const float* __restrict__ beta,
                      float* __restrict__ out) {
    int row = blockIdx.x;          // b*M3 + c
    int c = row & (M3 - 1);
    int b = row >> 7;
    __shared__ float sA, sB;
    int t = threadIdx.x;
    if (t == 0) {
        float s = 0.f, q = 0.f;
#pragma unroll 8
        for (int i = 0; i < NPB; ++i) { s += ps[c * NPB + i]; q += pq[c * NPB + i]; }
        float inv_n = 1.0f / (float)NPTS;
        float mean = s * inv_n;
        float var  = q * inv_n - mean * mean;
        float A = gamma[c] * rsqrtf(var + EPS);
        sA = A;
        sB = beta[c] - mean * A;
    }
    __syncthreads();
    float A = sA, Bb = sB;
    const float4 v = ((const float4*)(y3 + (size_t)c * NPTS + b * NP))[t];
    float4 r;
    r.x = fmaxf(v.x * A + Bb, 0.f);
    r.y = fmaxf(v.y * A + Bb, 0.f);
    r.z = fmaxf(v.z * A + Bb, 0.f);
    r.w = fmaxf(v.w * A + Bb, 0.f);
    ((float4*)(out + (size_t)row * NP))[t] = r;
}

extern "C" void kernel_launch(void* const* d_in, const int* in_sizes, int n_in,
                              void* d_out, int out_size, void* d_ws, size_t ws_size,
                              hipStream_t stream) {
    const float* points = (const float*)d_in[1];
    const float* onehot = (const float*)d_in[2];
    const int*   idx    = (const int*)d_in[3];
    const float* w1 = (const float*)d_in[4];
    const float* g1 = (const float*)d_in[5];
    const float* b1 = (const float*)d_in[6];
    const float* w2 = (const float*)d_in[7];
    const float* g2 = (const float*)d_in[8];
    const float* b2 = (const float*)d_in[9];
    const float* w3 = (const float*)d_in[10];
    const float* g3 = (const float*)d_in[11];
    const float* b3 = (const float*)d_in[12];

    float* out = (float*)d_out;
    float* ws  = (float*)d_ws;
    float* y1  = ws + Y1_OFF;
    float* y2  = ws + Y2_OFF;
    float* y3  = ws + Y3_OFF;
    float* ps1 = ws + PS1_OFF;  float* pq1 = ws + PQ1_OFF;
    float* ps2 = ws + PS2_OFF;  float* pq2 = ws + PQ2_OFF;
    float* ps3 = ws + PS3_OFF;  float* pq3 = ws + PQ3_OFF;

    const int T = 256;

    // 4-node pipeline (BN stats folded into producers/consumers)
    k1_gather<<<(M1 / OC1) * NPB, T, 0, stream>>>(points, onehot, idx, w1,
                                                  y1, ps1, pq1, (float4*)d_out);
    k_mlp<M1, M2, 8><<<(M2 / 8) * NPB, T, 0, stream>>>(y1, ps1, pq1, g1, b1, w2,
                                                       y2, ps2, pq2);
    k_mlp<M2, M3, 8><<<(M3 / 8) * NPB, T, 0, stream>>>(y2, ps2, pq2, g2, b2, w3,
                                                       y3, ps3, pq3);
    k_out<<<B * M3, T, 0, stream>>>(y3, ps3, pq3, g3, b3, out + GZ_ELEMS);
}